// Round 4
// baseline (194.207 us; speedup 1.0000x reference)
//
#include <hip/hip_runtime.h>
#include <hip/hip_bf16.h>

#define BINS 100
#define DIM 768
#define TPB 64        // tokens per block (compaction granularity)
#define NTHREADS 256
#define KPAD 128      // BINS padded to MFMA K multiple
#define PITCH 136     // ushort pitch for wbf rows: 272B, 16B-aligned
#define NDT 12        // d-tiles (16 cols) per wave: 48 tiles / 4 waves

// workspace byte offsets
#define OFF_ET   0         // ushort[768*128] = 196608 B
#define OFF_P    196608    // float[100] (512 B reserved)
#define OFF_Q    197120
#define OFF_TS   197632
#define OFF_KS   198144    // int[100]
#define OFF_R    198656    // int
#define OFF_W2P  198720    // float[100*100] = 40000 B (end 238720)
#define OFF_CNT  238720    // int survivor count (zeroed per launch)
#define OFF_LIST 238848    // int[T] survivor token ids (worst case 616448 B)

typedef __attribute__((ext_vector_type(8))) short bf16x8;
typedef __attribute__((ext_vector_type(4))) float f32x4;

__device__ __forceinline__ unsigned short f2bf(float x) {
    __hip_bfloat16 h = __float2bfloat16(x);
    return *reinterpret_cast<unsigned short*>(&h);
}
__device__ __forceinline__ float bfrt(float x) {   // bf16 round-trip (RNE)
    return __bfloat162float(__float2bfloat16(x));
}

// grid = DIM+1 blocks x 128 threads. Blocks [0,DIM): transpose emb -> bf16 ET.
// Block DIM: build P,Q (collapsed linear map), w2p = w2 + I, sorted thresholds.
__global__ void prep(const float* __restrict__ emb,
                     const float* __restrict__ w1,
                     const float* __restrict__ b1,
                     const float* __restrict__ w2,
                     const float* __restrict__ b2,
                     unsigned char* __restrict__ ws)
{
    const int bid = blockIdx.x;
    const int tid = threadIdx.x;
    if (bid < DIM) {
        unsigned short* et = (unsigned short*)(ws + OFF_ET);
        float v = (tid < BINS) ? emb[(long)tid * DIM + bid] : 0.f;
        et[bid * KPAD + tid] = f2bf(v);
        return;
    }
    __shared__ float pl[BINS], ql[BINS], tl[BINS];
    float* Pv  = (float*)(ws + OFF_P);
    float* Qv  = (float*)(ws + OFF_Q);
    float* ts  = (float*)(ws + OFF_TS);
    int*   ks  = (int*)  (ws + OFF_KS);
    int*   Rp  = (int*)  (ws + OFF_R);
    float* w2p = (float*)(ws + OFF_W2P);
    if (tid < BINS) {
        float w = w1[tid], b = b1[tid];
        // branch taken as x -> +inf (the "common" branch for x in [0,10])
        float f = (w > 0.f || (w == 0.f && b > 0.f)) ? 1.f : 0.1f;
        pl[tid] = w * f;
        ql[tid] = b * f;
        tl[tid] = (w != 0.f) ? (-b / w) : -1.f;   // breakpoint; w==0 never flips
    }
    __syncthreads();
    if (tid < BINS) {
        const int j = tid;
        float P = pl[j];            // alpha=1 direct term
        float Q = ql[j] + b2[j];
        for (int k = 0; k < BINS; k++) {
            float w = w2[j * BINS + k];
            P = fmaf(w, pl[k], P);
            Q = fmaf(w, ql[k], Q);
            w2p[j * BINS + k] = w + (j == k ? 1.f : 0.f);   // matmul + alpha*I
        }
        Pv[j] = P; Qv[j] = Q;
        // rank-sort thresholds descending
        float tk = tl[j];
        int rank = 0;
        for (int k2 = 0; k2 < BINS; k2++) {
            float t2 = tl[k2];
            rank += (t2 > tk || (t2 == tk && k2 < j)) ? 1 : 0;
        }
        ts[rank] = tk;
        ks[rank] = j;
    }
    if (tid == 0) {
        int R = 0;
        for (int k = 0; k < BINS; k++) R += (tl[k] > 0.f) ? 1 : 0;
        *Rp = R;
    }
}

// Pass A: masks -> override-row streaming writes + survivor list compaction.
__global__ __launch_bounds__(NTHREADS, 8)
void mask_kernel(const int* __restrict__ pad_mask,
                 const int* __restrict__ masked_mask,
                 const float* __restrict__ pad_emb,
                 const float* __restrict__ mask_emb,
                 float* __restrict__ out,
                 int* __restrict__ list,
                 int* __restrict__ cnt,
                 int T)
{
    __shared__ int olist[TPB];
    __shared__ int svl[TPB];
    __shared__ unsigned char ovr[TPB];
    __shared__ int Ssh, Osh, baseSh;

    const int tid  = threadIdx.x;
    const int lane = tid & 63;
    const int wave = tid >> 6;
    const long t0  = (long)blockIdx.x * TPB;
    const int nvalid = min(TPB, (int)(T - t0));

    if (wave == 0) {
        int o = 3; // out-of-range: neither computed nor written
        if (lane < nvalid) {
            int pm  = pad_mask[t0 + lane];
            int msk = masked_mask[t0 + lane];
            o = msk ? 2 : (pm ? 1 : 0);
        }
        ovr[lane] = (unsigned char)o;
        unsigned long long bs = __ballot(o == 0);
        unsigned long long bo = __ballot(o == 1 || o == 2);
        int si = __popcll(bs & ((1ull << lane) - 1ull));
        int oi = __popcll(bo & ((1ull << lane) - 1ull));
        if (o == 0) svl[si] = (int)(t0 + lane);
        if (o == 1 || o == 2) olist[oi] = lane;
        if (lane == 0) {
            Ssh = __popcll(bs);
            Osh = __popcll(bo);
            baseSh = Ssh ? atomicAdd(cnt, Ssh) : 0;
        }
    }
    __syncthreads();
    if (tid < Ssh) list[baseSh + tid] = svl[tid];

    float4 pev = {0,0,0,0}, mev = {0,0,0,0};
    if (tid < 192) {
        float4 p = ((const float4*)pad_emb)[tid];
        float4 m = ((const float4*)mask_emb)[tid];
        pev = make_float4(bfrt(p.x), bfrt(p.y), bfrt(p.z), bfrt(p.w));
        mev = make_float4(bfrt(m.x), bfrt(m.y), bfrt(m.z), bfrt(m.w));
    }
    const int O = Osh;
    for (int i = 0; i < O; i++) {
        int row = olist[i];
        if (tid < 192) {
            float4* orow = (float4*)(out + (t0 + row) * (long)DIM);
            orow[tid] = (ovr[row] == 2) ? mev : pev;
        }
    }
}

// Pass B: dense blocks of 64 survivors -> collapsed MLP + softmax + MFMA mix.
__global__ __launch_bounds__(NTHREADS, 6)
void surv_kernel(const float* __restrict__ gene,
                 const float* __restrict__ w1,
                 const float* __restrict__ b1,
                 const unsigned short* __restrict__ et,
                 const float* __restrict__ Pv,
                 const float* __restrict__ Qv,
                 const float* __restrict__ ts,
                 const int*   __restrict__ ksod,
                 const int*   __restrict__ Rp,
                 const float* __restrict__ w2p,
                 const int*   __restrict__ list,
                 const int*   __restrict__ cnt,
                 float* __restrict__ out)
{
    __shared__ unsigned short wbf[TPB][PITCH]; // bf16 softmax weights, K-padded
    __shared__ float xs[TPB];
    __shared__ int ids[TPB];

    const int total = *cnt;
    const int base = blockIdx.x * TPB;
    if (base >= total) return;
    const int valid = min(TPB, total - base);

    const int tid  = threadIdx.x;
    const int lane = tid & 63;
    const int wave = tid >> 6;

    if (tid < valid) {
        int id = list[base + tid];
        ids[tid] = id;
        xs[tid] = gene[id];
    }
    __syncthreads();

    // ---- collapsed MLP + softmax: token slot s handled by 4 lanes ----
    {
        int s = tid >> 2, part = tid & 3;
        const int j0 = part * 25;
        if (s < valid) {
            float x = xs[s];
            float v3[25];
            #pragma unroll
            for (int i = 0; i < 25; i++)
                v3[i] = fmaf(x, Pv[j0 + i], Qv[j0 + i]);
            const int R = *Rp;
            for (int idx = 0; idx < R; ++idx) {
                float t = ts[idx];
                if (t <= x) break;              // sorted desc: rest are common
                int k = ksod[idx];
                float v1 = fmaf(x, w1[k], b1[k]);
                float d = 0.9f * fabsf(v1);     // (f_actual - f_common)*v1
                const float* wc = w2p + j0 * BINS + k;
                #pragma unroll
                for (int i = 0; i < 25; i++)
                    v3[i] = fmaf(wc[i * BINS], d, v3[i]);
            }
            float vmax = -1e30f;
            #pragma unroll
            for (int i = 0; i < 25; i++) vmax = fmaxf(vmax, v3[i]);
            vmax = fmaxf(vmax, __shfl_xor(vmax, 1));
            vmax = fmaxf(vmax, __shfl_xor(vmax, 2));
            float sum = 0.f;
            #pragma unroll
            for (int i = 0; i < 25; i++) {
                v3[i] = __expf(v3[i] - vmax);
                sum += v3[i];
            }
            sum += __shfl_xor(sum, 1);
            sum += __shfl_xor(sum, 2);
            float inv = 1.f / sum;
            #pragma unroll
            for (int i = 0; i < 25; i++)
                wbf[s][j0 + i] = f2bf(v3[i] * inv);
            if (part == 3) {
                #pragma unroll
                for (int j = BINS; j < KPAD; j += 2)
                    *reinterpret_cast<unsigned int*>(&wbf[s][j]) = 0u;
            }
        }
    }
    __syncthreads();

    // ---- MFMA, swapped operands: A = ET d-rows, B = token weights ----
    // lane holds 4 consecutive d's of one token => float4 stores.
    const int SM = (valid + 15) >> 4;
    const int arow = lane & 15;
    const int kgrp = lane >> 4;
    int tok0, tok1, tok2, tok3;
    {
        int sl;
        sl = 0 * 16 + arow; tok0 = (sl < valid) ? ids[sl] : -1;
        sl = 1 * 16 + arow; tok1 = (SM > 1 && sl < valid) ? ids[sl] : -1;
        sl = 2 * 16 + arow; tok2 = (SM > 2 && sl < valid) ? ids[sl] : -1;
        sl = 3 * 16 + arow; tok3 = (SM > 3 && sl < valid) ? ids[sl] : -1;
    }
    for (int c = 0; c < NDT; c++) {
        int dt = (c * 4 + wave) * 16;          // this wave's 16-col d-tile
        const unsigned short* ap = et + (long)(dt + arow) * KPAD + kgrp * 8;
        bf16x8 afr[4];
        #pragma unroll
        for (int kss = 0; kss < 4; kss++)
            afr[kss] = *(const bf16x8*)(ap + kss * 32);
        #pragma unroll
        for (int mt = 0; mt < 4; mt++) {
            if (mt < SM) {
                f32x4 a = {0.f, 0.f, 0.f, 0.f};
                #pragma unroll
                for (int kss = 0; kss < 4; kss++) {
                    bf16x8 bfr = *(const bf16x8*)&wbf[mt * 16 + arow][kss * 32 + kgrp * 8];
                    a = __builtin_amdgcn_mfma_f32_16x16x32_bf16(afr[kss], bfr, a, 0, 0, 0);
                }
                int tkn = (mt == 0) ? tok0 : (mt == 1) ? tok1 : (mt == 2) ? tok2 : tok3;
                if (tkn >= 0)
                    *(float4*)(out + (long)tkn * DIM + dt + kgrp * 4)
                        = *reinterpret_cast<float4*>(&a);
            }
        }
    }
}

extern "C" void kernel_launch(void* const* d_in, const int* in_sizes, int n_in,
                              void* d_out, int out_size, void* d_ws, size_t ws_size,
                              hipStream_t stream) {
    const float* gene  = (const float*)d_in[0];
    const int*   pm    = (const int*)  d_in[1];
    const int*   mm    = (const int*)  d_in[2];
    const float* w1    = (const float*)d_in[3];
    const float* b1    = (const float*)d_in[4];
    const float* w2    = (const float*)d_in[5];
    const float* b2    = (const float*)d_in[6];
    const float* emb   = (const float*)d_in[7];
    const float* pade  = (const float*)d_in[8];
    const float* maske = (const float*)d_in[9];
    float* out = (float*)d_out;
    unsigned char* ws = (unsigned char*)d_ws;

    int T = in_sizes[0];                          // 8 * 19264 = 154112 tokens
    int nblk = (T + TPB - 1) / TPB;               // 2408

    hipMemsetAsync(ws + OFF_CNT, 0, sizeof(int), stream);
    hipLaunchKernelGGL(prep, dim3(DIM + 1), dim3(KPAD), 0, stream,
                       emb, w1, b1, w2, b2, ws);
    hipLaunchKernelGGL(mask_kernel, dim3(nblk), dim3(NTHREADS), 0, stream,
                       pm, mm, pade, maske, out,
                       (int*)(ws + OFF_LIST), (int*)(ws + OFF_CNT), T);
    hipLaunchKernelGGL(surv_kernel, dim3(nblk), dim3(NTHREADS), 0, stream,
                       gene, w1, b1,
                       (const unsigned short*)(ws + OFF_ET),
                       (const float*)(ws + OFF_P),
                       (const float*)(ws + OFF_Q),
                       (const float*)(ws + OFF_TS),
                       (const int*)(ws + OFF_KS),
                       (const int*)(ws + OFF_R),
                       (const float*)(ws + OFF_W2P),
                       (const int*)(ws + OFF_LIST),
                       (const int*)(ws + OFF_CNT),
                       out);
}

// Round 6
// 154.152 us; speedup vs baseline: 1.2598x; 1.2598x over previous
//
#include <hip/hip_runtime.h>
#include <hip/hip_bf16.h>

#define BINS 100
#define DIM 768
#define TPB 64        // tokens per block
#define NTHREADS 256
#define KPAD 128      // BINS padded to MFMA K multiple
#define PITCH 136     // ushort pitch for wbf rows: 272B, 16B-aligned
#define NDT 12        // d-tiles (16 cols) per wave: 48 tiles / 4 waves

// workspace byte offsets
#define OFF_ET   0         // ushort[768*128] = 196608 B
#define OFF_P    196608    // float[100] (512 B reserved)
#define OFF_Q    197120
#define OFF_TS   197632
#define OFF_KS   198144    // int[100]
#define OFF_R    198656    // int
#define OFF_W2P  198720    // float[100*100] = 40000 B (end 238720)

typedef __attribute__((ext_vector_type(8))) short bf16x8;
typedef __attribute__((ext_vector_type(4))) float f32x4;

__device__ __forceinline__ unsigned short f2bf(float x) {
    __hip_bfloat16 h = __float2bfloat16(x);
    return *reinterpret_cast<unsigned short*>(&h);
}
__device__ __forceinline__ float bfrt(float x) {   // bf16 round-trip (RNE)
    return __bfloat162float(__float2bfloat16(x));
}
__device__ __forceinline__ f32x4 bfrt4(f32x4 v) {
    f32x4 r;
    r.x = bfrt(v.x); r.y = bfrt(v.y); r.z = bfrt(v.z); r.w = bfrt(v.w);
    return r;
}

// grid = DIM+1 blocks x 128 threads. Blocks [0,DIM): transpose emb -> bf16 ET.
// Block DIM: build P,Q (collapsed linear map), w2p = w2 + I, sorted thresholds.
__global__ void prep(const float* __restrict__ emb,
                     const float* __restrict__ w1,
                     const float* __restrict__ b1,
                     const float* __restrict__ w2,
                     const float* __restrict__ b2,
                     unsigned char* __restrict__ ws)
{
    const int bid = blockIdx.x;
    const int tid = threadIdx.x;
    if (bid < DIM) {
        unsigned short* et = (unsigned short*)(ws + OFF_ET);
        float v = (tid < BINS) ? emb[(long)tid * DIM + bid] : 0.f;
        et[bid * KPAD + tid] = f2bf(v);
        return;
    }
    __shared__ float pl[BINS], ql[BINS], tl[BINS];
    float* Pv  = (float*)(ws + OFF_P);
    float* Qv  = (float*)(ws + OFF_Q);
    float* ts  = (float*)(ws + OFF_TS);
    int*   ks  = (int*)  (ws + OFF_KS);
    int*   Rp  = (int*)  (ws + OFF_R);
    float* w2p = (float*)(ws + OFF_W2P);
    if (tid < BINS) {
        float w = w1[tid], b = b1[tid];
        // branch taken as x -> +inf (the "common" branch for x in [0,10])
        float f = (w > 0.f || (w == 0.f && b > 0.f)) ? 1.f : 0.1f;
        pl[tid] = w * f;
        ql[tid] = b * f;
        tl[tid] = (w != 0.f) ? (-b / w) : -1.f;   // breakpoint; w==0 never flips
    }
    __syncthreads();
    if (tid < BINS) {
        const int j = tid;
        float P = pl[j];            // alpha=1 direct term
        float Q = ql[j] + b2[j];
        for (int k = 0; k < BINS; k++) {
            float w = w2[j * BINS + k];
            P = fmaf(w, pl[k], P);
            Q = fmaf(w, ql[k], Q);
            w2p[j * BINS + k] = w + (j == k ? 1.f : 0.f);   // matmul + alpha*I
        }
        Pv[j] = P; Qv[j] = Q;
        // rank-sort thresholds descending
        float tk = tl[j];
        int rank = 0;
        for (int k2 = 0; k2 < BINS; k2++) {
            float t2 = tl[k2];
            rank += (t2 > tk || (t2 == tk && k2 < j)) ? 1 : 0;
        }
        ts[rank] = tk;
        ks[rank] = j;
    }
    if (tid == 0) {
        int R = 0;
        for (int k = 0; k < BINS; k++) R += (tl[k] > 0.f) ? 1 : 0;
        *Rp = R;
    }
}

__global__ __launch_bounds__(NTHREADS, 8)
void ead_kernel(const float* __restrict__ gene,
                const int*   __restrict__ pad_mask,
                const int*   __restrict__ masked_mask,
                const float* __restrict__ w1,
                const float* __restrict__ b1,
                const unsigned short* __restrict__ et,
                const float* __restrict__ Pv,
                const float* __restrict__ Qv,
                const float* __restrict__ ts,
                const int*   __restrict__ ksod,
                const int*   __restrict__ Rp,
                const float* __restrict__ w2p,
                const float* __restrict__ pad_emb,
                const float* __restrict__ mask_emb,
                float* __restrict__ out,
                int T)
{
    __shared__ unsigned short wbf[TPB][PITCH]; // bf16 softmax weights, K-padded
    __shared__ float xs[TPB];
    __shared__ short surv[TPB];
    __shared__ short olist[TPB];   // row | (is_mask << 8)
    __shared__ int Ssh, Osh;

    const int tid  = threadIdx.x;
    const int lane = tid & 63;
    const int wave = tid >> 6;
    const long t0  = (long)blockIdx.x * TPB;
    const int nvalid = min(TPB, (int)(T - t0));

    // ---- step 1: masks, survivor + override compaction (wave 0) ----
    if (wave == 0) {
        int o = 3; // out-of-range: neither computed nor written
        if (lane < nvalid) {
            int pm  = pad_mask[t0 + lane];
            int msk = masked_mask[t0 + lane];
            o = msk ? 2 : (pm ? 1 : 0);
            xs[lane] = gene[t0 + lane];
        }
        unsigned long long bs = __ballot(o == 0);
        unsigned long long bo = __ballot(o == 1 || o == 2);
        int si = __popcll(bs & ((1ull << lane) - 1ull));
        int oi = __popcll(bo & ((1ull << lane) - 1ull));
        if (o == 0) surv[si] = (short)lane;
        if (o == 1 || o == 2) olist[oi] = (short)(lane | ((o == 2) ? 256 : 0));
        if (lane == 0) { Ssh = __popcll(bs); Osh = __popcll(bo); }
    }
    __syncthreads();
    const int S = Ssh, O = Osh;

    // ---- step 1.5: override rows, row-per-wave, full 3KB/row from registers ----
    {
        const f32x4* pe = (const f32x4*)pad_emb;
        const f32x4* me = (const f32x4*)mask_emb;
        f32x4 p0 = bfrt4(pe[lane]), p1 = bfrt4(pe[lane + 64]), p2 = bfrt4(pe[lane + 128]);
        f32x4 m0 = bfrt4(me[lane]), m1 = bfrt4(me[lane + 64]), m2 = bfrt4(me[lane + 128]);
        for (int i = wave; i < O; i += 4) {
            int e = olist[i];
            int row = e & 63;
            bool mm = (e & 256) != 0;
            f32x4* orow = (f32x4*)(out + (t0 + row) * (long)DIM);
            __builtin_nontemporal_store(mm ? m0 : p0, orow + lane);
            __builtin_nontemporal_store(mm ? m1 : p1, orow + lane + 64);
            __builtin_nontemporal_store(mm ? m2 : p2, orow + lane + 128);
        }
    }

    // ---- steps 2-4 collapsed: v3 = x*P + Q + rare-bin corrections; softmax ----
    {
        int s = tid >> 2, part = tid & 3;
        const int j0 = part * 25;
        if (s < S) {
            float x = xs[surv[s]];
            float v3[25];
            #pragma unroll
            for (int i = 0; i < 25; i++)
                v3[i] = fmaf(x, Pv[j0 + i], Qv[j0 + i]);
            const int R = *Rp;
            for (int idx = 0; idx < R; ++idx) {
                float t = ts[idx];
                if (t <= x) break;              // sorted desc: rest are common
                int k = ksod[idx];
                float v1 = fmaf(x, w1[k], b1[k]);
                float d = 0.9f * fabsf(v1);     // (f_actual - f_common)*v1
                const float* wc = w2p + j0 * BINS + k;
                #pragma unroll
                for (int i = 0; i < 25; i++)
                    v3[i] = fmaf(wc[i * BINS], d, v3[i]);
            }
            float vmax = -1e30f;
            #pragma unroll
            for (int i = 0; i < 25; i++) vmax = fmaxf(vmax, v3[i]);
            vmax = fmaxf(vmax, __shfl_xor(vmax, 1));
            vmax = fmaxf(vmax, __shfl_xor(vmax, 2));
            float sum = 0.f;
            #pragma unroll
            for (int i = 0; i < 25; i++) {
                v3[i] = __expf(v3[i] - vmax);
                sum += v3[i];
            }
            sum += __shfl_xor(sum, 1);
            sum += __shfl_xor(sum, 2);
            float inv = 1.f / sum;
            #pragma unroll
            for (int i = 0; i < 25; i++)
                wbf[s][j0 + i] = f2bf(v3[i] * inv);
            if (part == 3) {
                #pragma unroll
                for (int j = BINS; j < KPAD; j += 2)
                    *reinterpret_cast<unsigned int*>(&wbf[s][j]) = 0u;
            }
        }
    }
    __syncthreads();

    // ---- step 5: MFMA, swapped operands: A = ET d-rows, B = token weights ----
    // lane holds 4 consecutive d's of one token => float4 nt stores.
    const int SM = (S + 15) >> 4;
    if (SM > 0) {
        const int arow = lane & 15;
        const int kgrp = lane >> 4;
        int tok0, tok1, tok2, tok3;
        {
            int sl;
            sl = 0 * 16 + arow; tok0 = (sl < S) ? surv[sl] : -1;
            sl = 1 * 16 + arow; tok1 = (SM > 1 && sl < S) ? surv[sl] : -1;
            sl = 2 * 16 + arow; tok2 = (SM > 2 && sl < S) ? surv[sl] : -1;
            sl = 3 * 16 + arow; tok3 = (SM > 3 && sl < S) ? surv[sl] : -1;
        }
        for (int c = 0; c < NDT; c++) {
            int dt = (c * 4 + wave) * 16;          // this wave's 16-col d-tile
            const unsigned short* ap = et + (long)(dt + arow) * KPAD + kgrp * 8;
            bf16x8 afr[4];
            #pragma unroll
            for (int kss = 0; kss < 4; kss++)
                afr[kss] = *(const bf16x8*)(ap + kss * 32);
            #pragma unroll
            for (int mt = 0; mt < 4; mt++) {
                if (mt < SM) {
                    f32x4 a = {0.f, 0.f, 0.f, 0.f};
                    #pragma unroll
                    for (int kss = 0; kss < 4; kss++) {
                        bf16x8 bfr = *(const bf16x8*)&wbf[mt * 16 + arow][kss * 32 + kgrp * 8];
                        a = __builtin_amdgcn_mfma_f32_16x16x32_bf16(afr[kss], bfr, a, 0, 0, 0);
                    }
                    int tkn = (mt == 0) ? tok0 : (mt == 1) ? tok1 : (mt == 2) ? tok2 : tok3;
                    if (tkn >= 0) {
                        f32x4* dst = (f32x4*)(out + (t0 + tkn) * (long)DIM + dt + kgrp * 4);
                        __builtin_nontemporal_store(a, dst);
                    }
                }
            }
        }
    }
}

extern "C" void kernel_launch(void* const* d_in, const int* in_sizes, int n_in,
                              void* d_out, int out_size, void* d_ws, size_t ws_size,
                              hipStream_t stream) {
    const float* gene  = (const float*)d_in[0];
    const int*   pm    = (const int*)  d_in[1];
    const int*   mm    = (const int*)  d_in[2];
    const float* w1    = (const float*)d_in[3];
    const float* b1    = (const float*)d_in[4];
    const float* w2    = (const float*)d_in[5];
    const float* b2    = (const float*)d_in[6];
    const float* emb   = (const float*)d_in[7];
    const float* pade  = (const float*)d_in[8];
    const float* maske = (const float*)d_in[9];
    float* out = (float*)d_out;
    unsigned char* ws = (unsigned char*)d_ws;

    int T = in_sizes[0];                          // 8 * 19264 = 154112 tokens
    int nblk = (T + TPB - 1) / TPB;               // 2408

    hipLaunchKernelGGL(prep, dim3(DIM + 1), dim3(KPAD), 0, stream,
                       emb, w1, b1, w2, b2, ws);
    hipLaunchKernelGGL(ead_kernel, dim3(nblk), dim3(NTHREADS), 0, stream,
                       gene, pm, mm, w1, b1,
                       (const unsigned short*)(ws + OFF_ET),
                       (const float*)(ws + OFF_P),
                       (const float*)(ws + OFF_Q),
                       (const float*)(ws + OFF_TS),
                       (const int*)(ws + OFF_KS),
                       (const int*)(ws + OFF_R),
                       (const float*)(ws + OFF_W2P),
                       pade, maske, out, T);
}

// Round 7
// 148.162 us; speedup vs baseline: 1.3108x; 1.0404x over previous
//
#include <hip/hip_runtime.h>
#include <hip/hip_bf16.h>

#define BINS 100
#define DIM 768
#define TPB 64        // tokens per block
#define NTHREADS 256
#define KPAD 128      // BINS padded to MFMA K multiple
#define PITCH 136     // ushort pitch for wbf rows: 272B, 16B-aligned
#define NDT 12        // chunks per wave: each wave owns 192 contiguous floats/row

// workspace byte offsets
#define OFF_ET   0         // ushort[768*128] = 196608 B
#define OFF_P    196608    // float[100] (512 B reserved)
#define OFF_Q    197120
#define OFF_TS   197632
#define OFF_KS   198144    // int[100]
#define OFF_R    198656    // int
#define OFF_W2P  198720    // float[100*100] = 40000 B (end 238720)

typedef __attribute__((ext_vector_type(8))) short bf16x8;
typedef __attribute__((ext_vector_type(4))) float f32x4;

__device__ __forceinline__ unsigned short f2bf(float x) {
    __hip_bfloat16 h = __float2bfloat16(x);
    return *reinterpret_cast<unsigned short*>(&h);
}
__device__ __forceinline__ float bfrt(float x) {   // bf16 round-trip (RNE)
    return __bfloat162float(__float2bfloat16(x));
}
__device__ __forceinline__ f32x4 bfrt4(f32x4 v) {
    f32x4 r;
    r.x = bfrt(v.x); r.y = bfrt(v.y); r.z = bfrt(v.z); r.w = bfrt(v.w);
    return r;
}

// grid = DIM+1 blocks x 128 threads. Blocks [0,DIM): transpose emb -> bf16 ET.
// Block DIM: build P,Q (collapsed linear map), w2p = w2 + I, sorted thresholds.
__global__ void prep(const float* __restrict__ emb,
                     const float* __restrict__ w1,
                     const float* __restrict__ b1,
                     const float* __restrict__ w2,
                     const float* __restrict__ b2,
                     unsigned char* __restrict__ ws)
{
    const int bid = blockIdx.x;
    const int tid = threadIdx.x;
    if (bid < DIM) {
        unsigned short* et = (unsigned short*)(ws + OFF_ET);
        float v = (tid < BINS) ? emb[(long)tid * DIM + bid] : 0.f;
        et[bid * KPAD + tid] = f2bf(v);
        return;
    }
    __shared__ float pl[BINS], ql[BINS], tl[BINS];
    float* Pv  = (float*)(ws + OFF_P);
    float* Qv  = (float*)(ws + OFF_Q);
    float* ts  = (float*)(ws + OFF_TS);
    int*   ks  = (int*)  (ws + OFF_KS);
    int*   Rp  = (int*)  (ws + OFF_R);
    float* w2p = (float*)(ws + OFF_W2P);
    if (tid < BINS) {
        float w = w1[tid], b = b1[tid];
        // branch taken as x -> +inf (the "common" branch for x in [0,10])
        float f = (w > 0.f || (w == 0.f && b > 0.f)) ? 1.f : 0.1f;
        pl[tid] = w * f;
        ql[tid] = b * f;
        tl[tid] = (w != 0.f) ? (-b / w) : -1.f;   // breakpoint; w==0 never flips
    }
    __syncthreads();
    if (tid < BINS) {
        const int j = tid;
        float P = pl[j];            // alpha=1 direct term
        float Q = ql[j] + b2[j];
        for (int k = 0; k < BINS; k++) {
            float w = w2[j * BINS + k];
            P = fmaf(w, pl[k], P);
            Q = fmaf(w, ql[k], Q);
            w2p[j * BINS + k] = w + (j == k ? 1.f : 0.f);   // matmul + alpha*I
        }
        Pv[j] = P; Qv[j] = Q;
        // rank-sort thresholds descending
        float tk = tl[j];
        int rank = 0;
        for (int k2 = 0; k2 < BINS; k2++) {
            float t2 = tl[k2];
            rank += (t2 > tk || (t2 == tk && k2 < j)) ? 1 : 0;
        }
        ts[rank] = tk;
        ks[rank] = j;
    }
    if (tid == 0) {
        int R = 0;
        for (int k = 0; k < BINS; k++) R += (tl[k] > 0.f) ? 1 : 0;
        *Rp = R;
    }
}

__global__ __launch_bounds__(NTHREADS, 8)
void ead_kernel(const float* __restrict__ gene,
                const int*   __restrict__ pad_mask,
                const int*   __restrict__ masked_mask,
                const float* __restrict__ w1,
                const float* __restrict__ b1,
                const unsigned short* __restrict__ et,
                const float* __restrict__ Pv,
                const float* __restrict__ Qv,
                const float* __restrict__ ts,
                const int*   __restrict__ ksod,
                const int*   __restrict__ Rp,
                const float* __restrict__ w2p,
                const float* __restrict__ pad_emb,
                const float* __restrict__ mask_emb,
                float* __restrict__ out,
                int T)
{
    __shared__ unsigned short wbf[TPB][PITCH]; // bf16 softmax weights, K-padded
    __shared__ float xs[TPB];
    __shared__ short surv[TPB];
    __shared__ short olist[TPB];   // row | (is_mask << 8)
    __shared__ int Ssh, Osh;

    const int tid  = threadIdx.x;
    const int lane = tid & 63;
    const int wave = tid >> 6;
    const long t0  = (long)blockIdx.x * TPB;
    const int nvalid = min(TPB, (int)(T - t0));

    // ---- step 1: masks, survivor + override compaction (wave 0) ----
    if (wave == 0) {
        int o = 3; // out-of-range: neither computed nor written
        if (lane < nvalid) {
            int pm  = pad_mask[t0 + lane];
            int msk = masked_mask[t0 + lane];
            o = msk ? 2 : (pm ? 1 : 0);
            xs[lane] = gene[t0 + lane];
        }
        unsigned long long bs = __ballot(o == 0);
        unsigned long long bo = __ballot(o == 1 || o == 2);
        int si = __popcll(bs & ((1ull << lane) - 1ull));
        int oi = __popcll(bo & ((1ull << lane) - 1ull));
        if (o == 0) surv[si] = (short)lane;
        if (o == 1 || o == 2) olist[oi] = (short)(lane | ((o == 2) ? 256 : 0));
        if (lane == 0) { Ssh = __popcll(bs); Osh = __popcll(bo); }
    }
    __syncthreads();
    const int S = Ssh, O = Osh;

    // ---- step 1.5: override rows, row-per-wave, full 3KB/row from registers ----
    {
        const f32x4* pe = (const f32x4*)pad_emb;
        const f32x4* me = (const f32x4*)mask_emb;
        f32x4 p0 = bfrt4(pe[lane]), p1 = bfrt4(pe[lane + 64]), p2 = bfrt4(pe[lane + 128]);
        f32x4 m0 = bfrt4(me[lane]), m1 = bfrt4(me[lane + 64]), m2 = bfrt4(me[lane + 128]);
        for (int i = wave; i < O; i += 4) {
            int e = olist[i];
            int row = e & 63;
            bool mm = (e & 256) != 0;
            f32x4* orow = (f32x4*)(out + (t0 + row) * (long)DIM);
            __builtin_nontemporal_store(mm ? m0 : p0, orow + lane);
            __builtin_nontemporal_store(mm ? m1 : p1, orow + lane + 64);
            __builtin_nontemporal_store(mm ? m2 : p2, orow + lane + 128);
        }
    }

    // ---- steps 2-4 collapsed: v3 = x*P + Q + rare-bin corrections; softmax ----
    // slot s = wave + 4*(lane>>2): spreads slots across all 4 waves/SIMDs;
    // 4-lane shuffle partners stay within the wave.
    {
        int s = wave + 4 * (lane >> 2);
        int part = lane & 3;
        const int j0 = part * 25;
        if (s < S) {
            float x = xs[surv[s]];
            float v3[25];
            #pragma unroll
            for (int i = 0; i < 25; i++)
                v3[i] = fmaf(x, Pv[j0 + i], Qv[j0 + i]);
            const int R = *Rp;
            for (int idx = 0; idx < R; ++idx) {
                float t = ts[idx];
                if (t <= x) break;              // sorted desc: rest are common
                int k = ksod[idx];
                float v1 = fmaf(x, w1[k], b1[k]);
                float d = 0.9f * fabsf(v1);     // (f_actual - f_common)*v1
                const float* wc = w2p + j0 * BINS + k;
                #pragma unroll
                for (int i = 0; i < 25; i++)
                    v3[i] = fmaf(wc[i * BINS], d, v3[i]);
            }
            float vmax = -1e30f;
            #pragma unroll
            for (int i = 0; i < 25; i++) vmax = fmaxf(vmax, v3[i]);
            vmax = fmaxf(vmax, __shfl_xor(vmax, 1));
            vmax = fmaxf(vmax, __shfl_xor(vmax, 2));
            float sum = 0.f;
            #pragma unroll
            for (int i = 0; i < 25; i++) {
                v3[i] = __expf(v3[i] - vmax);
                sum += v3[i];
            }
            sum += __shfl_xor(sum, 1);
            sum += __shfl_xor(sum, 2);
            float inv = 1.f / sum;
            #pragma unroll
            for (int i = 0; i < 25; i++)
                wbf[s][j0 + i] = f2bf(v3[i] * inv);
            if (part == 3) {
                #pragma unroll
                for (int j = BINS; j < KPAD; j += 2)
                    *reinterpret_cast<unsigned int*>(&wbf[s][j]) = 0u;
            }
        }
    }
    __syncthreads();

    // ---- step 5: MFMA, swapped operands: A = ET d-rows, B = token weights ----
    // Each wave owns a CONTIGUOUS 192-float span of every row (dt = wave*192 +
    // c*16): consecutive c iterations write adjacent 64B halves of the same
    // 128B L2 line close in time -> full-line merge before HBM writeback.
    const int SM = (S + 15) >> 4;
    if (SM > 0) {
        const int arow = lane & 15;
        const int kgrp = lane >> 4;
        int tok0, tok1, tok2, tok3;
        {
            int sl;
            sl = 0 * 16 + arow; tok0 = (sl < S) ? surv[sl] : -1;
            sl = 1 * 16 + arow; tok1 = (SM > 1 && sl < S) ? surv[sl] : -1;
            sl = 2 * 16 + arow; tok2 = (SM > 2 && sl < S) ? surv[sl] : -1;
            sl = 3 * 16 + arow; tok3 = (SM > 3 && sl < S) ? surv[sl] : -1;
        }
        for (int c = 0; c < NDT; c++) {
            int dt = wave * 192 + c * 16;          // contiguous span per wave
            const unsigned short* ap = et + (long)(dt + arow) * KPAD + kgrp * 8;
            bf16x8 afr[4];
            #pragma unroll
            for (int kss = 0; kss < 4; kss++)
                afr[kss] = *(const bf16x8*)(ap + kss * 32);
            #pragma unroll
            for (int mt = 0; mt < 4; mt++) {
                if (mt < SM) {
                    f32x4 a = {0.f, 0.f, 0.f, 0.f};
                    #pragma unroll
                    for (int kss = 0; kss < 4; kss++) {
                        bf16x8 bfr = *(const bf16x8*)&wbf[mt * 16 + arow][kss * 32 + kgrp * 8];
                        a = __builtin_amdgcn_mfma_f32_16x16x32_bf16(afr[kss], bfr, a, 0, 0, 0);
                    }
                    int tkn = (mt == 0) ? tok0 : (mt == 1) ? tok1 : (mt == 2) ? tok2 : tok3;
                    if (tkn >= 0)
                        *(f32x4*)(out + (t0 + tkn) * (long)DIM + dt + kgrp * 4) = a;
                }
            }
        }
    }
}

extern "C" void kernel_launch(void* const* d_in, const int* in_sizes, int n_in,
                              void* d_out, int out_size, void* d_ws, size_t ws_size,
                              hipStream_t stream) {
    const float* gene  = (const float*)d_in[0];
    const int*   pm    = (const int*)  d_in[1];
    const int*   mm    = (const int*)  d_in[2];
    const float* w1    = (const float*)d_in[3];
    const float* b1    = (const float*)d_in[4];
    const float* w2    = (const float*)d_in[5];
    const float* b2    = (const float*)d_in[6];
    const float* emb   = (const float*)d_in[7];
    const float* pade  = (const float*)d_in[8];
    const float* maske = (const float*)d_in[9];
    float* out = (float*)d_out;
    unsigned char* ws = (unsigned char*)d_ws;

    int T = in_sizes[0];                          // 8 * 19264 = 154112 tokens
    int nblk = (T + TPB - 1) / TPB;               // 2408

    hipLaunchKernelGGL(prep, dim3(DIM + 1), dim3(KPAD), 0, stream,
                       emb, w1, b1, w2, b2, ws);
    hipLaunchKernelGGL(ead_kernel, dim3(nblk), dim3(NTHREADS), 0, stream,
                       gene, pm, mm, w1, b1,
                       (const unsigned short*)(ws + OFF_ET),
                       (const float*)(ws + OFF_P),
                       (const float*)(ws + OFF_Q),
                       (const float*)(ws + OFF_TS),
                       (const int*)(ws + OFF_KS),
                       (const int*)(ws + OFF_R),
                       (const float*)(ws + OFF_W2P),
                       pade, maske, out, T);
}